// Round 4
// baseline (315.566 us; speedup 1.0000x reference)
//
#include <hip/hip_runtime.h>

#define HDIM 1024
#define TDIM 17
#define BDIM 64
#define SDIM 512
#define NROWS (BDIM * SDIM) /* 32768 */
#define NCH 8
#define CHL 64

// ---------------------------------------------------------------------------
// Kernel 1: feats = x @ W^T + b.
// R4: latency-bound fix. 32 rows/block (was 64) -> 1024 blocks = 4 blocks/CU
// = 4 waves/SIMD (was 2); __launch_bounds__(256,4) caps VGPR at 128 so the
// occupancy is realized; 2-deep software pipeline on x loads (issue c+1
// before computing c). Per-row FMA order unchanged -> feats bitwise
// identical to R3.
// ---------------------------------------------------------------------------
__global__ __launch_bounds__(256, 4) void gemm_kernel(
    const float* __restrict__ x, const float* __restrict__ W,
    const float* __restrict__ bias, float* __restrict__ feats) {
  __shared__ __align__(16) float sW[TDIM * 512];  // 34816 B
  int tid = threadIdx.x;
  int sub = tid & 15;  // K-phase within row
  int g = tid >> 4;    // row-group 0..15
  int row0 = blockIdx.x * 32 + g * 2;
  const float* xr = x + (size_t)row0 * HDIM;
  float acc[2][TDIM];
#pragma unroll
  for (int r = 0; r < 2; ++r)
#pragma unroll
    for (int t = 0; t < TDIM; ++t) acc[r][t] = 0.f;

  for (int ph = 0; ph < 2; ++ph) {
    if (ph) __syncthreads();  // WAR: previous phase done reading sW
    // stage W[t][ph*512 .. +511]: 2176 float4, 256 threads -> 8.5 each
    for (int i = tid; i < TDIM * 128; i += 256) {
      int t = i >> 7;
      int k = (i & 127) * 4;
      *(float4*)&sW[t * 512 + k] =
          *(const float4*)&W[(size_t)t * HDIM + ph * 512 + k];
    }
    __syncthreads();
    float4 xv[2], xn[2];
#pragma unroll
    for (int r = 0; r < 2; ++r)
      xv[r] = *(const float4*)(xr + r * HDIM + ph * 512 + sub * 4);
#pragma unroll
    for (int c = 0; c < 8; ++c) {
      if (c < 7) {
#pragma unroll
        for (int r = 0; r < 2; ++r)
          xn[r] =
              *(const float4*)(xr + r * HDIM + ph * 512 + (c + 1) * 64 + sub * 4);
      }
#pragma unroll
      for (int t = 0; t < TDIM; ++t) {
        float4 wv = *(const float4*)&sW[t * 512 + c * 64 + sub * 4];
#pragma unroll
        for (int r = 0; r < 2; ++r) {
          float a = acc[r][t];
          a = fmaf(xv[r].x, wv.x, a);
          a = fmaf(xv[r].y, wv.y, a);
          a = fmaf(xv[r].z, wv.z, a);
          a = fmaf(xv[r].w, wv.w, a);
          acc[r][t] = a;
        }
      }
#pragma unroll
      for (int r = 0; r < 2; ++r) xv[r] = xn[r];
    }
  }
  // reduce across the 16-lane K-group (xor masks < 16 stay in-group)
#pragma unroll
  for (int r = 0; r < 2; ++r)
#pragma unroll
    for (int t = 0; t < TDIM; ++t) {
#pragma unroll
      for (int m = 1; m < 16; m <<= 1)
        acc[r][t] += __shfl_xor(acc[r][t], m, 64);
    }
#pragma unroll
  for (int r = 0; r < 2; ++r) {
    float val = acc[r][0];
#pragma unroll
    for (int t = 1; t < 16; ++t) val = (sub == t) ? acc[r][t] : val;
    feats[(size_t)(row0 + r) * TDIM + sub] = val + bias[sub];
    if (sub == 0)
      feats[(size_t)(row0 + r) * TDIM + 16] = acc[r][16] + bias[16];
  }
}

// ---------------------------------------------------------------------------
// 17-value max tree (max3-fused). maxv is bitwise one of v[0..16].
// ---------------------------------------------------------------------------
__device__ __forceinline__ float vmax17(const float* v) {
  float m0 = fmaxf(fmaxf(v[0], v[1]), v[2]);
  float m1 = fmaxf(fmaxf(v[3], v[4]), v[5]);
  float m2 = fmaxf(fmaxf(v[6], v[7]), v[8]);
  float m3 = fmaxf(fmaxf(v[9], v[10]), v[11]);
  float m4 = fmaxf(fmaxf(v[12], v[13]), v[14]);
  float m5 = fmaxf(v[15], v[16]);
  float n0 = fmaxf(fmaxf(m0, m1), m2);
  float n1 = fmaxf(fmaxf(m3, m4), m5);
  return fmaxf(n0, n1);
}

// ---------------------------------------------------------------------------
// P1: per-chunk max-plus product (ensemble of 17 unit vectors). (unchanged)
// ---------------------------------------------------------------------------
__global__ __launch_bounds__(384) void chunkprod_kernel(
    const float* __restrict__ feats, const float* __restrict__ trans,
    const int* __restrict__ nwords, float* __restrict__ Pbuf) {
  int bc = blockIdx.x;
  int b = bc >> 3, c = bc & 7;
  int nw = nwords[b];
  if (nw < 1) nw = 1;
  if (nw > SDIM) nw = SDIM;
  if (c > 0 && c * CHL > nw - 1) return;  // chunk fully masked
  int tid = threadIdx.x;
  int wid = tid >> 6, lane = tid & 63;
  int g = lane / 17, j = lane % 17;
  int gc = g < 3 ? g : 2;
  int e = wid * 3 + gc;
  int ibase = gc * 17 * 4;
  const float* fb = feats + (size_t)b * SDIM * TDIM;
  float tcol[TDIM];
#pragma unroll
  for (int i = 0; i < TDIM; ++i) tcol[i] = trans[i * TDIM + j];
  float s = (j == e) ? 0.f : -1e30f;
  int t_start = (c == 0) ? 1 : c * CHL;
  int t_end = c * CHL + CHL - 1;
  if (t_end > nw - 1) t_end = nw - 1;
  int tA = t_start;
  int tB = t_start + 1;
  if (tB > t_end) tB = t_start;
  float fA = fb[(size_t)tA * TDIM + j];
  float fB = fb[(size_t)tB * TDIM + j];
  for (int t = t_start; t <= t_end; ++t) {
    int t2 = t + 2;
    if (t2 > t_end) t2 = t_end;
    float fC = fb[(size_t)t2 * TDIM + j];
    int sb = __float_as_int(s);
    float v[TDIM];
#pragma unroll
    for (int i = 0; i < TDIM; ++i)
      v[i] = __int_as_float(__builtin_amdgcn_ds_bpermute(ibase + 4 * i, sb)) +
             tcol[i];
    float maxv = vmax17(v);
    s = maxv + fA;
    fA = fB;
    fB = fC;
  }
  if (g < 3 && e < TDIM)
    Pbuf[((size_t)(b * NCH + c) * TDIM + e) * TDIM + j] = s;
}

// ---------------------------------------------------------------------------
// P2: scan over chunk products -> boundary vectors + final tag. (unchanged)
// ---------------------------------------------------------------------------
__global__ __launch_bounds__(64) void scan_kernel(
    const float* __restrict__ feats, const float* __restrict__ start_t,
    const float* __restrict__ end_t, const int* __restrict__ nwords,
    const float* __restrict__ Pbuf, float* __restrict__ bnd,
    int* __restrict__ elast) {
  int b = blockIdx.x;
  int lane = threadIdx.x;
  int jj = lane < TDIM ? lane : TDIM - 1;
  int nw = nwords[b];
  if (nw < 1) nw = 1;
  if (nw > SDIM) nw = SDIM;
  int clast = (nw - 1) >> 6;
  float w = start_t[jj] + feats[(size_t)b * SDIM * TDIM + jj];  // s(0)
  for (int c = 0; c <= clast; ++c) {
    const float* Pc = Pbuf + (size_t)(b * NCH + c) * TDIM * TDIM;
    float pj[TDIM];
#pragma unroll
    for (int i = 0; i < TDIM; ++i) pj[i] = Pc[i * TDIM + jj];
    int wb = __float_as_int(w);
    float v[TDIM];
#pragma unroll
    for (int i = 0; i < TDIM; ++i)
      v[i] = __int_as_float(__builtin_amdgcn_ds_bpermute(4 * i, wb)) + pj[i];
    w = vmax17(v);
    if (lane < TDIM) bnd[(b * NCH + c) * TDIM + lane] = w;
  }
  float fin = w + end_t[jj];
  float tmax = (lane < TDIM) ? fin : -1e30f;
#pragma unroll
  for (int m = 1; m < 64; m <<= 1) tmax = fmaxf(tmax, __shfl_xor(tmax, m, 64));
  unsigned long long mm = __ballot(fin == tmax) & 0x1FFFFull;
  if (lane == 0) elast[b] = (int)(__ffsll((unsigned long long)mm) - 1);
}

// ---------------------------------------------------------------------------
// P3: re-run chunks from true boundary vectors; parallel 17-tag chase.
// (unchanged)
// ---------------------------------------------------------------------------
__global__ __launch_bounds__(64) void rerun_kernel(
    const float* __restrict__ feats, const float* __restrict__ trans,
    const float* __restrict__ start_t, const int* __restrict__ nwords,
    const float* __restrict__ bnd, int* __restrict__ etag,
    unsigned* __restrict__ seq32) {
  __shared__ unsigned char s_bp[CHL * 20];
  __shared__ __align__(4) unsigned char s_seq[TDIM * 68];
  int bc = blockIdx.x;
  int b = bc >> 3, c = bc & 7;
  int nw = nwords[b];
  if (nw < 1) nw = 1;
  if (nw > SDIM) nw = SDIM;
  if (c > 0 && c * CHL > nw - 1) return;
  int lane = threadIdx.x;
  int jj = lane < TDIM ? lane : TDIM - 1;
  const float* fb = feats + (size_t)b * SDIM * TDIM;
  float tcol[TDIM];
#pragma unroll
  for (int i = 0; i < TDIM; ++i) tcol[i] = trans[i * TDIM + jj];
  float sj = (c == 0) ? (start_t[jj] + fb[jj])
                      : bnd[(b * NCH + c - 1) * TDIM + jj];
  int t_start = (c == 0) ? 1 : c * CHL;
  int t_end = c * CHL + CHL - 1;
  if (t_end > nw - 1) t_end = nw - 1;
  int tA = t_start;
  int tB = t_start + 1;
  if (tB > t_end) tB = t_start;
  float fA = fb[(size_t)tA * TDIM + jj];
  float fB = fb[(size_t)tB * TDIM + jj];
  for (int t = t_start; t <= t_end; ++t) {
    int t2 = t + 2;
    if (t2 > t_end) t2 = t_end;
    float fC = fb[(size_t)t2 * TDIM + jj];
    int sb = __float_as_int(sj);
    float v[TDIM];
#pragma unroll
    for (int i = 0; i < TDIM; ++i)
      v[i] = __int_as_float(__builtin_amdgcn_ds_bpermute(4 * i, sb)) + tcol[i];
    float maxv = vmax17(v);
    unsigned msk = 0;
#pragma unroll
    for (int i = 0; i < TDIM; ++i) msk |= (v[i] == maxv) ? (1u << i) : 0u;
    int bp = __ffs(msk) - 1;
    s_bp[(t - c * CHL) * 20 + jj] = (unsigned char)bp;
    sj = maxv + fA;
    fA = fB;
    fB = fC;
  }
  __syncthreads();
  if (lane < TDIM) {
    int tag = lane;
    for (int t = t_end; t >= t_start; --t) {
      int u = t - c * CHL;
      s_seq[lane * 68 + u] = (unsigned char)tag;
      tag = s_bp[u * 20 + tag];
    }
    if (c == 0)
      s_seq[lane * 68 + 0] = (unsigned char)tag;
    else
      etag[(b * NCH + c) * TDIM + lane] = tag;
  }
  __syncthreads();
  for (int i = lane; i < TDIM * 16; i += 64) {
    int e2 = i >> 4, q = i & 15;
    seq32[(((size_t)(b * NCH + c) * TDIM + e2) << 4) + q] =
        *(const unsigned*)&s_seq[e2 * 68 + q * 4];
  }
}

// ---------------------------------------------------------------------------
// P4: stitch chunks, emit tags. (unchanged)
// ---------------------------------------------------------------------------
__global__ __launch_bounds__(64) void stitch_kernel(
    const int* __restrict__ nwords, const int* __restrict__ elast,
    const int* __restrict__ etag, const unsigned* __restrict__ seq32,
    float* __restrict__ tags_out) {
  __shared__ unsigned long long stz[64];
  int b = blockIdx.x;
  int lane = threadIdx.x;
  int nw = nwords[b];
  if (nw < 1) nw = 1;
  if (nw > SDIM) nw = SDIM;
  stz[lane] = 0ull;
  __syncthreads();
  unsigned char* st = (unsigned char*)stz;
  int clast = (nw - 1) >> 6;
  int e = elast[b];
  for (int c = clast; c >= 0; --c) {
    int t_end = c * CHL + CHL - 1;
    if (t_end > nw - 1) t_end = nw - 1;
    int u_end = t_end - c * CHL;
    if (lane < 16) {
      unsigned wv = seq32[(((size_t)(b * NCH + c) * TDIM + e) << 4) + lane];
#pragma unroll
      for (int z = 0; z < 4; ++z) {
        int u = lane * 4 + z;
        if (u <= u_end) st[c * CHL + u] = (wv >> (8 * z)) & 0xff;
      }
    }
    if (c > 0) e = etag[(b * NCH + c) * TDIM + e];
  }
  __syncthreads();
  float* ob = tags_out + (size_t)b * SDIM;
  for (int t = lane; t < SDIM; t += 64)
    ob[t] = (t < nw) ? (float)st[t] : 0.f;
}

// ---------------------------------------------------------------------------
// Fallback: R2 single-kernel Viterbi (used only if workspace too small).
// ---------------------------------------------------------------------------
#define TRS 20
#define MVC 136

__global__ __launch_bounds__(64) void viterbi_kernel(
    const float* __restrict__ feats, const float* __restrict__ trans,
    const float* __restrict__ start_t, const float* __restrict__ end_t,
    const int* __restrict__ nwords, float* __restrict__ tags_out) {
  __shared__ __align__(16) float s_mv[64 * MVC];
  __shared__ float s_tr[TDIM * TRS];
  __shared__ unsigned char s_tags[SDIM];
  int b = blockIdx.x;
  int lane = threadIdx.x;
  const float* fb = feats + (size_t)b * SDIM * TDIM;
  for (int i = lane; i < TDIM * TDIM; i += 64)
    s_tr[(i / TDIM) * TRS + (i % TDIM)] = trans[i];
  __syncthreads();
  int nw = nwords[b];
  if (nw < 1) nw = 1;
  if (nw > SDIM) nw = SDIM;
  int jj = lane < TDIM ? lane : TDIM - 1;
  float tcol[TDIM];
#pragma unroll
  for (int i = 0; i < TDIM; ++i) tcol[i] = trans[i * TDIM + jj];
  float s[TDIM];
#pragma unroll
  for (int i = 0; i < TDIM; ++i) s[i] = start_t[i] + fb[i];
  float s0reg = start_t[jj] + fb[jj];
  auto load8g = [&](float* f, int t) {
#pragma unroll
    for (int u = 0; u < 8; ++u) f[u] = fb[(size_t)(t + u) * TDIM + jj];
  };
  auto step = [&](float fcu) -> float {
    float v[TDIM];
#pragma unroll
    for (int i = 0; i < TDIM; ++i) v[i] = s[i] + tcol[i];
    float maxv = vmax17(v);
    float ns = maxv + fcu;
#pragma unroll
    for (int i = 0; i < TDIM; ++i)
      s[i] = __uint_as_float(
          (unsigned)__builtin_amdgcn_readlane((int)__float_as_uint(ns), i));
    return maxv;
  };
  float fc[8], fn[8], mvr[8];
  load8g(fc, 0);
  {
    load8g(fn, 8);
    mvr[0] = 0.f;
#pragma unroll
    for (int u = 1; u < 8; ++u) {
      mvr[u] = 0.f;
      if (u < nw) mvr[u] = step(fc[u]);
    }
    if (lane < TDIM) {
      *(float4*)&s_mv[lane * 8] = make_float4(mvr[0], mvr[1], mvr[2], mvr[3]);
      *(float4*)&s_mv[lane * 8 + 4] =
          make_float4(mvr[4], mvr[5], mvr[6], mvr[7]);
    }
#pragma unroll
    for (int u = 0; u < 8; ++u) fc[u] = fn[u];
  }
  int t0 = 8;
  for (; t0 + 8 <= nw; t0 += 8) {
    int tn = (t0 + 8 <= SDIM - 8) ? t0 + 8 : t0;
    load8g(fn, tn);
#pragma unroll
    for (int u = 0; u < 8; ++u) mvr[u] = step(fc[u]);
    int cb = (t0 >> 3) * MVC;
    if (lane < TDIM) {
      *(float4*)&s_mv[cb + lane * 8] =
          make_float4(mvr[0], mvr[1], mvr[2], mvr[3]);
      *(float4*)&s_mv[cb + lane * 8 + 4] =
          make_float4(mvr[4], mvr[5], mvr[6], mvr[7]);
    }
#pragma unroll
    for (int u = 0; u < 8; ++u) fc[u] = fn[u];
  }
  if (t0 < nw) {
#pragma unroll
    for (int u = 0; u < 8; ++u) {
      mvr[u] = 0.f;
      if (t0 + u < nw) mvr[u] = step(fc[u]);
    }
    int cb = (t0 >> 3) * MVC;
    if (lane < TDIM) {
      *(float4*)&s_mv[cb + lane * 8] =
          make_float4(mvr[0], mvr[1], mvr[2], mvr[3]);
      *(float4*)&s_mv[cb + lane * 8 + 4] =
          make_float4(mvr[4], mvr[5], mvr[6], mvr[7]);
    }
  }
  float bv = s[0] + end_t[0];
  int bi = 0;
#pragma unroll
  for (int j = 1; j < TDIM; ++j) {
    float cc = s[j] + end_t[j];
    bool p = cc > bv;
    bv = p ? cc : bv;
    bi = p ? j : bi;
  }
  int tag = __builtin_amdgcn_readfirstlane(bi);
  s_tags[nw - 1] = (unsigned char)tag;
  {
    int t = nw - 1;
    int ip = t - 1 > 0 ? t - 1 : 0;
    float fv = fb[(size_t)ip * TDIM + jj];
    float mvv = s_mv[(ip >> 3) * MVC + jj * 8 + (ip & 7)];
    while (t >= 1) {
      float tr = s_tr[jj * TRS + tag];
      float target = s_mv[(t >> 3) * MVC + tag * 8 + (t & 7)];
      int inx = t - 2 > 0 ? t - 2 : 0;
      float fvn = fb[(size_t)inx * TDIM + jj];
      float mvn = s_mv[(inx >> 3) * MVC + jj * 8 + (inx & 7)];
      float sv = (t - 1 == 0) ? s0reg : (mvv + fv);
      float cand = sv + tr;
      unsigned long long m = __ballot(cand == target) & 0x1FFFFull;
      tag = __ffsll(m) - 1;
      s_tags[t - 1] = (unsigned char)tag;
      fv = fvn;
      mvv = mvn;
      --t;
    }
  }
  __syncthreads();
  float* ob = tags_out + (size_t)b * SDIM;
  for (int t = lane; t < SDIM; t += 64)
    ob[t] = (t < nw) ? (float)s_tags[t] : 0.f;
}

// ---------------------------------------------------------------------------
// Workspace layout (bytes):
//   P    : 64*8*17*17*4 = 591872
//   bnd  : 64*8*17*4    =  34816   @ 591872
//   elast: 64*4         =    256   @ 626688
//   etag : 64*8*17*4    =  34816   @ 626944
//   seq  : 64*8*17*64   = 557056   @ 661760
//   total               = 1218816
// ---------------------------------------------------------------------------
extern "C" void kernel_launch(void* const* d_in, const int* in_sizes, int n_in,
                              void* d_out, int out_size, void* d_ws,
                              size_t ws_size, hipStream_t stream) {
  const float* x = (const float*)d_in[0];
  const float* W = (const float*)d_in[1];
  const float* b = (const float*)d_in[2];
  const float* trans = (const float*)d_in[3];
  const float* start_t = (const float*)d_in[4];
  const float* end_t = (const float*)d_in[5];
  const int* nwords = (const int*)d_in[6];
  float* out = (float*)d_out;
  float* tags_out = out;           // (B, S)
  float* feats_out = out + NROWS;  // (B, S, T)

  gemm_kernel<<<NROWS / 32, 256, 0, stream>>>(x, W, b, feats_out);

  if (ws_size >= (size_t)1218816 && d_ws != nullptr) {
    char* ws = (char*)d_ws;
    float* Pbuf = (float*)(ws);
    float* bnd = (float*)(ws + 591872);
    int* elast = (int*)(ws + 626688);
    int* etag = (int*)(ws + 626944);
    unsigned* seq32 = (unsigned*)(ws + 661760);
    chunkprod_kernel<<<BDIM * NCH, 384, 0, stream>>>(feats_out, trans, nwords,
                                                     Pbuf);
    scan_kernel<<<BDIM, 64, 0, stream>>>(feats_out, start_t, end_t, nwords,
                                         Pbuf, bnd, elast);
    rerun_kernel<<<BDIM * NCH, 64, 0, stream>>>(feats_out, trans, start_t,
                                                nwords, bnd, etag, seq32);
    stitch_kernel<<<BDIM, 64, 0, stream>>>(nwords, elast, etag, seq32,
                                           tags_out);
  } else {
    viterbi_kernel<<<BDIM, 64, 0, stream>>>(feats_out, trans, start_t, end_t,
                                            nwords, tags_out);
  }
}

// Round 5
// 287.432 us; speedup vs baseline: 1.0979x; 1.0979x over previous
//
#include <hip/hip_runtime.h>

#define HDIM 1024
#define TDIM 17
#define BDIM 64
#define SDIM 512
#define NROWS (BDIM * SDIM) /* 32768 */
#define NCH 8
#define CHL 64

// ---------------------------------------------------------------------------
// Kernel 1: feats = x @ W^T + b.
// R5: same shape as R4 (32 rows/block, r=2, grid 1024 -> 4 blocks/CU via the
// natural LDS cap of 34.8KB), but NO min-waves clause: R4's
// __launch_bounds__(256,4) forced VGPR to 64 and spilled to scratch
// (WRITE_SIZE 2.2MB -> 64MB, the whole regression). Unconstrained r=2 needs
// ~100 VGPR -> 4 waves/SIMD with zero spill. 2-deep x prefetch kept.
// ---------------------------------------------------------------------------
__global__ __launch_bounds__(256) void gemm_kernel(
    const float* __restrict__ x, const float* __restrict__ W,
    const float* __restrict__ bias, float* __restrict__ feats) {
  __shared__ __align__(16) float sW[TDIM * 512];  // 34816 B -> 4 blocks/CU
  int tid = threadIdx.x;
  int sub = tid & 15;  // K-phase within row
  int g = tid >> 4;    // row-group 0..15
  int row0 = blockIdx.x * 32 + g * 2;
  const float* xr = x + (size_t)row0 * HDIM;
  float acc[2][TDIM];
#pragma unroll
  for (int r = 0; r < 2; ++r)
#pragma unroll
    for (int t = 0; t < TDIM; ++t) acc[r][t] = 0.f;

  for (int ph = 0; ph < 2; ++ph) {
    if (ph) __syncthreads();  // WAR: previous phase done reading sW
    // stage W[t][ph*512 .. +511]: 2176 float4, 256 threads -> 8.5 each
    for (int i = tid; i < TDIM * 128; i += 256) {
      int t = i >> 7;
      int k = (i & 127) * 4;
      *(float4*)&sW[t * 512 + k] =
          *(const float4*)&W[(size_t)t * HDIM + ph * 512 + k];
    }
    __syncthreads();
    float4 xv[2], xn[2];
#pragma unroll
    for (int r = 0; r < 2; ++r)
      xv[r] = *(const float4*)(xr + r * HDIM + ph * 512 + sub * 4);
#pragma unroll
    for (int c = 0; c < 8; ++c) {
      if (c < 7) {
#pragma unroll
        for (int r = 0; r < 2; ++r)
          xn[r] =
              *(const float4*)(xr + r * HDIM + ph * 512 + (c + 1) * 64 + sub * 4);
      }
#pragma unroll
      for (int t = 0; t < TDIM; ++t) {
        float4 wv = *(const float4*)&sW[t * 512 + c * 64 + sub * 4];
#pragma unroll
        for (int r = 0; r < 2; ++r) {
          float a = acc[r][t];
          a = fmaf(xv[r].x, wv.x, a);
          a = fmaf(xv[r].y, wv.y, a);
          a = fmaf(xv[r].z, wv.z, a);
          a = fmaf(xv[r].w, wv.w, a);
          acc[r][t] = a;
        }
      }
#pragma unroll
      for (int r = 0; r < 2; ++r) xv[r] = xn[r];
    }
  }
  // reduce across the 16-lane K-group (xor masks < 16 stay in-group)
#pragma unroll
  for (int r = 0; r < 2; ++r)
#pragma unroll
    for (int t = 0; t < TDIM; ++t) {
#pragma unroll
      for (int m = 1; m < 16; m <<= 1)
        acc[r][t] += __shfl_xor(acc[r][t], m, 64);
    }
#pragma unroll
  for (int r = 0; r < 2; ++r) {
    float val = acc[r][0];
#pragma unroll
    for (int t = 1; t < 16; ++t) val = (sub == t) ? acc[r][t] : val;
    feats[(size_t)(row0 + r) * TDIM + sub] = val + bias[sub];
    if (sub == 0)
      feats[(size_t)(row0 + r) * TDIM + 16] = acc[r][16] + bias[16];
  }
}

// ---------------------------------------------------------------------------
// 17-value max tree (max3-fused). maxv is bitwise one of v[0..16].
// ---------------------------------------------------------------------------
__device__ __forceinline__ float vmax17(const float* v) {
  float m0 = fmaxf(fmaxf(v[0], v[1]), v[2]);
  float m1 = fmaxf(fmaxf(v[3], v[4]), v[5]);
  float m2 = fmaxf(fmaxf(v[6], v[7]), v[8]);
  float m3 = fmaxf(fmaxf(v[9], v[10]), v[11]);
  float m4 = fmaxf(fmaxf(v[12], v[13]), v[14]);
  float m5 = fmaxf(v[15], v[16]);
  float n0 = fmaxf(fmaxf(m0, m1), m2);
  float n1 = fmaxf(fmaxf(m3, m4), m5);
  return fmaxf(n0, n1);
}

// ---------------------------------------------------------------------------
// P1: per-chunk max-plus product (ensemble of 17 unit vectors). (unchanged)
// ---------------------------------------------------------------------------
__global__ __launch_bounds__(384) void chunkprod_kernel(
    const float* __restrict__ feats, const float* __restrict__ trans,
    const int* __restrict__ nwords, float* __restrict__ Pbuf) {
  int bc = blockIdx.x;
  int b = bc >> 3, c = bc & 7;
  int nw = nwords[b];
  if (nw < 1) nw = 1;
  if (nw > SDIM) nw = SDIM;
  if (c > 0 && c * CHL > nw - 1) return;  // chunk fully masked
  int tid = threadIdx.x;
  int wid = tid >> 6, lane = tid & 63;
  int g = lane / 17, j = lane % 17;
  int gc = g < 3 ? g : 2;
  int e = wid * 3 + gc;
  int ibase = gc * 17 * 4;
  const float* fb = feats + (size_t)b * SDIM * TDIM;
  float tcol[TDIM];
#pragma unroll
  for (int i = 0; i < TDIM; ++i) tcol[i] = trans[i * TDIM + j];
  float s = (j == e) ? 0.f : -1e30f;
  int t_start = (c == 0) ? 1 : c * CHL;
  int t_end = c * CHL + CHL - 1;
  if (t_end > nw - 1) t_end = nw - 1;
  int tA = t_start;
  int tB = t_start + 1;
  if (tB > t_end) tB = t_start;
  float fA = fb[(size_t)tA * TDIM + j];
  float fB = fb[(size_t)tB * TDIM + j];
  for (int t = t_start; t <= t_end; ++t) {
    int t2 = t + 2;
    if (t2 > t_end) t2 = t_end;
    float fC = fb[(size_t)t2 * TDIM + j];
    int sb = __float_as_int(s);
    float v[TDIM];
#pragma unroll
    for (int i = 0; i < TDIM; ++i)
      v[i] = __int_as_float(__builtin_amdgcn_ds_bpermute(ibase + 4 * i, sb)) +
             tcol[i];
    float maxv = vmax17(v);
    s = maxv + fA;
    fA = fB;
    fB = fC;
  }
  if (g < 3 && e < TDIM)
    Pbuf[((size_t)(b * NCH + c) * TDIM + e) * TDIM + j] = s;
}

// ---------------------------------------------------------------------------
// P2: scan over chunk products -> boundary vectors + final tag. (unchanged)
// ---------------------------------------------------------------------------
__global__ __launch_bounds__(64) void scan_kernel(
    const float* __restrict__ feats, const float* __restrict__ start_t,
    const float* __restrict__ end_t, const int* __restrict__ nwords,
    const float* __restrict__ Pbuf, float* __restrict__ bnd,
    int* __restrict__ elast) {
  int b = blockIdx.x;
  int lane = threadIdx.x;
  int jj = lane < TDIM ? lane : TDIM - 1;
  int nw = nwords[b];
  if (nw < 1) nw = 1;
  if (nw > SDIM) nw = SDIM;
  int clast = (nw - 1) >> 6;
  float w = start_t[jj] + feats[(size_t)b * SDIM * TDIM + jj];  // s(0)
  for (int c = 0; c <= clast; ++c) {
    const float* Pc = Pbuf + (size_t)(b * NCH + c) * TDIM * TDIM;
    float pj[TDIM];
#pragma unroll
    for (int i = 0; i < TDIM; ++i) pj[i] = Pc[i * TDIM + jj];
    int wb = __float_as_int(w);
    float v[TDIM];
#pragma unroll
    for (int i = 0; i < TDIM; ++i)
      v[i] = __int_as_float(__builtin_amdgcn_ds_bpermute(4 * i, wb)) + pj[i];
    w = vmax17(v);
    if (lane < TDIM) bnd[(b * NCH + c) * TDIM + lane] = w;
  }
  float fin = w + end_t[jj];
  float tmax = (lane < TDIM) ? fin : -1e30f;
#pragma unroll
  for (int m = 1; m < 64; m <<= 1) tmax = fmaxf(tmax, __shfl_xor(tmax, m, 64));
  unsigned long long mm = __ballot(fin == tmax) & 0x1FFFFull;
  if (lane == 0) elast[b] = (int)(__ffsll((unsigned long long)mm) - 1);
}

// ---------------------------------------------------------------------------
// P3: re-run chunks from true boundary vectors; parallel 17-tag chase.
// (unchanged)
// ---------------------------------------------------------------------------
__global__ __launch_bounds__(64) void rerun_kernel(
    const float* __restrict__ feats, const float* __restrict__ trans,
    const float* __restrict__ start_t, const int* __restrict__ nwords,
    const float* __restrict__ bnd, int* __restrict__ etag,
    unsigned* __restrict__ seq32) {
  __shared__ unsigned char s_bp[CHL * 20];
  __shared__ __align__(4) unsigned char s_seq[TDIM * 68];
  int bc = blockIdx.x;
  int b = bc >> 3, c = bc & 7;
  int nw = nwords[b];
  if (nw < 1) nw = 1;
  if (nw > SDIM) nw = SDIM;
  if (c > 0 && c * CHL > nw - 1) return;
  int lane = threadIdx.x;
  int jj = lane < TDIM ? lane : TDIM - 1;
  const float* fb = feats + (size_t)b * SDIM * TDIM;
  float tcol[TDIM];
#pragma unroll
  for (int i = 0; i < TDIM; ++i) tcol[i] = trans[i * TDIM + jj];
  float sj = (c == 0) ? (start_t[jj] + fb[jj])
                      : bnd[(b * NCH + c - 1) * TDIM + jj];
  int t_start = (c == 0) ? 1 : c * CHL;
  int t_end = c * CHL + CHL - 1;
  if (t_end > nw - 1) t_end = nw - 1;
  int tA = t_start;
  int tB = t_start + 1;
  if (tB > t_end) tB = t_start;
  float fA = fb[(size_t)tA * TDIM + jj];
  float fB = fb[(size_t)tB * TDIM + jj];
  for (int t = t_start; t <= t_end; ++t) {
    int t2 = t + 2;
    if (t2 > t_end) t2 = t_end;
    float fC = fb[(size_t)t2 * TDIM + jj];
    int sb = __float_as_int(sj);
    float v[TDIM];
#pragma unroll
    for (int i = 0; i < TDIM; ++i)
      v[i] = __int_as_float(__builtin_amdgcn_ds_bpermute(4 * i, sb)) + tcol[i];
    float maxv = vmax17(v);
    unsigned msk = 0;
#pragma unroll
    for (int i = 0; i < TDIM; ++i) msk |= (v[i] == maxv) ? (1u << i) : 0u;
    int bp = __ffs(msk) - 1;
    s_bp[(t - c * CHL) * 20 + jj] = (unsigned char)bp;
    sj = maxv + fA;
    fA = fB;
    fB = fC;
  }
  __syncthreads();
  if (lane < TDIM) {
    int tag = lane;
    for (int t = t_end; t >= t_start; --t) {
      int u = t - c * CHL;
      s_seq[lane * 68 + u] = (unsigned char)tag;
      tag = s_bp[u * 20 + tag];
    }
    if (c == 0)
      s_seq[lane * 68 + 0] = (unsigned char)tag;
    else
      etag[(b * NCH + c) * TDIM + lane] = tag;
  }
  __syncthreads();
  for (int i = lane; i < TDIM * 16; i += 64) {
    int e2 = i >> 4, q = i & 15;
    seq32[(((size_t)(b * NCH + c) * TDIM + e2) << 4) + q] =
        *(const unsigned*)&s_seq[e2 * 68 + q * 4];
  }
}

// ---------------------------------------------------------------------------
// P4: stitch chunks, emit tags. (unchanged)
// ---------------------------------------------------------------------------
__global__ __launch_bounds__(64) void stitch_kernel(
    const int* __restrict__ nwords, const int* __restrict__ elast,
    const int* __restrict__ etag, const unsigned* __restrict__ seq32,
    float* __restrict__ tags_out) {
  __shared__ unsigned long long stz[64];
  int b = blockIdx.x;
  int lane = threadIdx.x;
  int nw = nwords[b];
  if (nw < 1) nw = 1;
  if (nw > SDIM) nw = SDIM;
  stz[lane] = 0ull;
  __syncthreads();
  unsigned char* st = (unsigned char*)stz;
  int clast = (nw - 1) >> 6;
  int e = elast[b];
  for (int c = clast; c >= 0; --c) {
    int t_end = c * CHL + CHL - 1;
    if (t_end > nw - 1) t_end = nw - 1;
    int u_end = t_end - c * CHL;
    if (lane < 16) {
      unsigned wv = seq32[(((size_t)(b * NCH + c) * TDIM + e) << 4) + lane];
#pragma unroll
      for (int z = 0; z < 4; ++z) {
        int u = lane * 4 + z;
        if (u <= u_end) st[c * CHL + u] = (wv >> (8 * z)) & 0xff;
      }
    }
    if (c > 0) e = etag[(b * NCH + c) * TDIM + e];
  }
  __syncthreads();
  float* ob = tags_out + (size_t)b * SDIM;
  for (int t = lane; t < SDIM; t += 64)
    ob[t] = (t < nw) ? (float)st[t] : 0.f;
}

// ---------------------------------------------------------------------------
// Fallback: R2 single-kernel Viterbi (used only if workspace too small).
// ---------------------------------------------------------------------------
#define TRS 20
#define MVC 136

__global__ __launch_bounds__(64) void viterbi_kernel(
    const float* __restrict__ feats, const float* __restrict__ trans,
    const float* __restrict__ start_t, const float* __restrict__ end_t,
    const int* __restrict__ nwords, float* __restrict__ tags_out) {
  __shared__ __align__(16) float s_mv[64 * MVC];
  __shared__ float s_tr[TDIM * TRS];
  __shared__ unsigned char s_tags[SDIM];
  int b = blockIdx.x;
  int lane = threadIdx.x;
  const float* fb = feats + (size_t)b * SDIM * TDIM;
  for (int i = lane; i < TDIM * TDIM; i += 64)
    s_tr[(i / TDIM) * TRS + (i % TDIM)] = trans[i];
  __syncthreads();
  int nw = nwords[b];
  if (nw < 1) nw = 1;
  if (nw > SDIM) nw = SDIM;
  int jj = lane < TDIM ? lane : TDIM - 1;
  float tcol[TDIM];
#pragma unroll
  for (int i = 0; i < TDIM; ++i) tcol[i] = trans[i * TDIM + jj];
  float s[TDIM];
#pragma unroll
  for (int i = 0; i < TDIM; ++i) s[i] = start_t[i] + fb[i];
  float s0reg = start_t[jj] + fb[jj];
  auto load8g = [&](float* f, int t) {
#pragma unroll
    for (int u = 0; u < 8; ++u) f[u] = fb[(size_t)(t + u) * TDIM + jj];
  };
  auto step = [&](float fcu) -> float {
    float v[TDIM];
#pragma unroll
    for (int i = 0; i < TDIM; ++i) v[i] = s[i] + tcol[i];
    float maxv = vmax17(v);
    float ns = maxv + fcu;
#pragma unroll
    for (int i = 0; i < TDIM; ++i)
      s[i] = __uint_as_float(
          (unsigned)__builtin_amdgcn_readlane((int)__float_as_uint(ns), i));
    return maxv;
  };
  float fc[8], fn[8], mvr[8];
  load8g(fc, 0);
  {
    load8g(fn, 8);
    mvr[0] = 0.f;
#pragma unroll
    for (int u = 1; u < 8; ++u) {
      mvr[u] = 0.f;
      if (u < nw) mvr[u] = step(fc[u]);
    }
    if (lane < TDIM) {
      *(float4*)&s_mv[lane * 8] = make_float4(mvr[0], mvr[1], mvr[2], mvr[3]);
      *(float4*)&s_mv[lane * 8 + 4] =
          make_float4(mvr[4], mvr[5], mvr[6], mvr[7]);
    }
#pragma unroll
    for (int u = 0; u < 8; ++u) fc[u] = fn[u];
  }
  int t0 = 8;
  for (; t0 + 8 <= nw; t0 += 8) {
    int tn = (t0 + 8 <= SDIM - 8) ? t0 + 8 : t0;
    load8g(fn, tn);
#pragma unroll
    for (int u = 0; u < 8; ++u) mvr[u] = step(fc[u]);
    int cb = (t0 >> 3) * MVC;
    if (lane < TDIM) {
      *(float4*)&s_mv[cb + lane * 8] =
          make_float4(mvr[0], mvr[1], mvr[2], mvr[3]);
      *(float4*)&s_mv[cb + lane * 8 + 4] =
          make_float4(mvr[4], mvr[5], mvr[6], mvr[7]);
    }
#pragma unroll
    for (int u = 0; u < 8; ++u) fc[u] = fn[u];
  }
  if (t0 < nw) {
#pragma unroll
    for (int u = 0; u < 8; ++u) {
      mvr[u] = 0.f;
      if (t0 + u < nw) mvr[u] = step(fc[u]);
    }
    int cb = (t0 >> 3) * MVC;
    if (lane < TDIM) {
      *(float4*)&s_mv[cb + lane * 8] =
          make_float4(mvr[0], mvr[1], mvr[2], mvr[3]);
      *(float4*)&s_mv[cb + lane * 8 + 4] =
          make_float4(mvr[4], mvr[5], mvr[6], mvr[7]);
    }
  }
  float bv = s[0] + end_t[0];
  int bi = 0;
#pragma unroll
  for (int j = 1; j < TDIM; ++j) {
    float cc = s[j] + end_t[j];
    bool p = cc > bv;
    bv = p ? cc : bv;
    bi = p ? j : bi;
  }
  int tag = __builtin_amdgcn_readfirstlane(bi);
  s_tags[nw - 1] = (unsigned char)tag;
  {
    int t = nw - 1;
    int ip = t - 1 > 0 ? t - 1 : 0;
    float fv = fb[(size_t)ip * TDIM + jj];
    float mvv = s_mv[(ip >> 3) * MVC + jj * 8 + (ip & 7)];
    while (t >= 1) {
      float tr = s_tr[jj * TRS + tag];
      float target = s_mv[(t >> 3) * MVC + tag * 8 + (t & 7)];
      int inx = t - 2 > 0 ? t - 2 : 0;
      float fvn = fb[(size_t)inx * TDIM + jj];
      float mvn = s_mv[(inx >> 3) * MVC + jj * 8 + (inx & 7)];
      float sv = (t - 1 == 0) ? s0reg : (mvv + fv);
      float cand = sv + tr;
      unsigned long long m = __ballot(cand == target) & 0x1FFFFull;
      tag = __ffsll(m) - 1;
      s_tags[t - 1] = (unsigned char)tag;
      fv = fvn;
      mvv = mvn;
      --t;
    }
  }
  __syncthreads();
  float* ob = tags_out + (size_t)b * SDIM;
  for (int t = lane; t < SDIM; t += 64)
    ob[t] = (t < nw) ? (float)s_tags[t] : 0.f;
}

// ---------------------------------------------------------------------------
// Workspace layout (bytes):
//   P    : 64*8*17*17*4 = 591872
//   bnd  : 64*8*17*4    =  34816   @ 591872
//   elast: 64*4         =    256   @ 626688
//   etag : 64*8*17*4    =  34816   @ 626944
//   seq  : 64*8*17*64   = 557056   @ 661760
//   total               = 1218816
// ---------------------------------------------------------------------------
extern "C" void kernel_launch(void* const* d_in, const int* in_sizes, int n_in,
                              void* d_out, int out_size, void* d_ws,
                              size_t ws_size, hipStream_t stream) {
  const float* x = (const float*)d_in[0];
  const float* W = (const float*)d_in[1];
  const float* b = (const float*)d_in[2];
  const float* trans = (const float*)d_in[3];
  const float* start_t = (const float*)d_in[4];
  const float* end_t = (const float*)d_in[5];
  const int* nwords = (const int*)d_in[6];
  float* out = (float*)d_out;
  float* tags_out = out;           // (B, S)
  float* feats_out = out + NROWS;  // (B, S, T)

  gemm_kernel<<<NROWS / 32, 256, 0, stream>>>(x, W, b, feats_out);

  if (ws_size >= (size_t)1218816 && d_ws != nullptr) {
    char* ws = (char*)d_ws;
    float* Pbuf = (float*)(ws);
    float* bnd = (float*)(ws + 591872);
    int* elast = (int*)(ws + 626688);
    int* etag = (int*)(ws + 626944);
    unsigned* seq32 = (unsigned*)(ws + 661760);
    chunkprod_kernel<<<BDIM * NCH, 384, 0, stream>>>(feats_out, trans, nwords,
                                                     Pbuf);
    scan_kernel<<<BDIM, 64, 0, stream>>>(feats_out, start_t, end_t, nwords,
                                         Pbuf, bnd, elast);
    rerun_kernel<<<BDIM * NCH, 64, 0, stream>>>(feats_out, trans, start_t,
                                                nwords, bnd, etag, seq32);
    stitch_kernel<<<BDIM, 64, 0, stream>>>(nwords, elast, etag, seq32,
                                           tags_out);
  } else {
    viterbi_kernel<<<BDIM, 64, 0, stream>>>(feats_out, trans, start_t, end_t,
                                            nwords, tags_out);
  }
}